// Round 3
// baseline (11135.315 us; speedup 1.0000x reference)
//
#include <hip/hip_runtime.h>
#include <hip/hip_bf16.h>

#define N_PTS 1048576
#define RES 192
#define R3 (RES*RES*RES)
#define NCH 28

#define BXC 32
#define BYC 8
#define BZC 8
#define CX (RES/BXC)              // 6
#define CY (RES/BYC)              // 24
#define CZ (RES/BZC)              // 24
#define NCELLS (CX*CY*CZ)         // 3456
#define NPRIV 8
#define NBUCKETS (NCELLS+1)
#define HIST_ENTRIES (NBUCKETS*NPRIV)

#define NBLK_MAIN 1024
#define PER_BLOCK (N_PTS/NBLK_MAIN)   // 1024

__device__ __forceinline__ unsigned point_key(float xx, float xy, float xz) {
    if (fabsf(xx) < 1.5f && fabsf(xy) < 1.5f && fabsf(xz) < 1.5f) {
        float cx = fminf(fmaxf(xx / 1.5f, -1.f), 1.f);
        float cy = fminf(fmaxf(xy / 1.5f, -1.f), 1.f);
        float cz = fminf(fmaxf(xz / 1.5f, -1.f), 1.f);
        int ix = (int)(((cx + 1.f) * 0.5f) * (float)(RES - 1));
        int iy = (int)(((cy + 1.f) * 0.5f) * (float)(RES - 1));
        int iz = (int)(((cz + 1.f) * 0.5f) * (float)(RES - 1));
        ix = min(ix, RES - 1); iy = min(iy, RES - 1); iz = min(iz, RES - 1);
        return ((unsigned)(iz / BZC) * CY + (unsigned)(iy / BYC)) * CX + (unsigned)(ix / BXC);
    }
    return (unsigned)NCELLS;
}

__global__ __launch_bounds__(256) void k_count(const float* __restrict__ x,
                                               unsigned* __restrict__ key,
                                               unsigned* __restrict__ hist) {
    unsigned i = blockIdx.x * 256 + threadIdx.x;
    if (i >= N_PTS) return;
    float xx = x[3*i+0], xy = x[3*i+1], xz = x[3*i+2];
    unsigned k = point_key(xx, xy, xz);
    key[i] = k;
    atomicAdd(&hist[k * NPRIV + (blockIdx.x & (NPRIV - 1))], 1u);
}

__global__ __launch_bounds__(1024) void k_scan(unsigned* __restrict__ hist) {
    __shared__ unsigned s[1024];
    const int TOT = HIST_ENTRIES;
    const int CHUNK = (TOT + 1023) / 1024;
    int t = threadIdx.x;
    int beg = t * CHUNK;
    int end = min(beg + CHUNK, TOT);
    unsigned sum = 0;
    for (int u = beg; u < end; ++u) sum += hist[u];
    s[t] = sum;
    __syncthreads();
    for (int off = 1; off < 1024; off *= 2) {
        unsigned v = (t >= off) ? s[t - off] : 0u;
        __syncthreads();
        s[t] += v;
        __syncthreads();
    }
    unsigned run = (t > 0) ? s[t - 1] : 0u;
    for (int u = beg; u < end; ++u) {
        unsigned h = hist[u];
        hist[u] = run;
        run += h;
    }
}

__global__ __launch_bounds__(256) void k_scatter(const unsigned* __restrict__ key,
                                                 unsigned* __restrict__ hist,
                                                 unsigned* __restrict__ perm) {
    unsigned i = blockIdx.x * 256 + threadIdx.x;
    if (i >= N_PTS) return;
    unsigned k = key[i];
    unsigned pos = atomicAdd(&hist[k * NPRIV + (blockIdx.x & (NPRIV - 1))], 1u);
    if (pos < (unsigned)N_PTS) perm[pos] = i;
}

template <bool SORTED>
__global__ __launch_bounds__(256) void k_main(const float* __restrict__ x,
                                              const float* __restrict__ dvec,
                                              const float* __restrict__ grid,
                                              const unsigned* __restrict__ perm,
                                              float* __restrict__ out) {
    unsigned start = blockIdx.x * PER_BLOCK;
    for (unsigned t = threadIdx.x; t < PER_BLOCK; t += 256) {
        unsigned j = start + t;
        unsigned i = SORTED ? perm[j] : j;
        if (i >= (unsigned)N_PTS) continue;   // defensive: never follow a bad index

        float xx = x[3*i+0], xy = x[3*i+1], xz = x[3*i+2];
        float sigma = 0.f, a0 = 0.f, a1 = 0.f, a2 = 0.f;

        if (fabsf(xx) < 1.5f && fabsf(xy) < 1.5f && fabsf(xz) < 1.5f) {
            float cx = fminf(fmaxf(xx / 1.5f, -1.f), 1.f);
            float cy = fminf(fmaxf(xy / 1.5f, -1.f), 1.f);
            float cz = fminf(fmaxf(xz / 1.5f, -1.f), 1.f);
            float px = ((cx + 1.f) * 0.5f) * (float)(RES - 1);
            float py = ((cy + 1.f) * 0.5f) * (float)(RES - 1);
            float pz = ((cz + 1.f) * 0.5f) * (float)(RES - 1);
            float fx = floorf(px), fy = floorf(py), fz = floorf(pz);
            float wx = px - fx, wy = py - fy, wz = pz - fz;
            int ix0 = min((int)fx, RES - 1);
            int iy0 = min((int)fy, RES - 1);
            int iz0 = min((int)fz, RES - 1);
            int ix1 = min(ix0 + 1, RES - 1);
            int iy1 = min(iy0 + 1, RES - 1);
            int iz1 = min(iz0 + 1, RES - 1);

            int o000 = (iz0 * RES + iy0) * RES + ix0;
            int dX = ix1 - ix0;
            int dY = (iy1 - iy0) * RES;
            int dZ = (iz1 - iz0) * RES * RES;
            int o001 = o000 + dX,      o010 = o000 + dY,      o011 = o000 + dY + dX;
            int o100 = o000 + dZ,      o101 = o000 + dZ + dX;
            int o110 = o000 + dZ + dY, o111 = o000 + dZ + dY + dX;

            float mx = 1.f - wx, my = 1.f - wy, mz = 1.f - wz;
            float w000 = mx*my*mz, w001 = wx*my*mz, w010 = mx*wy*mz, w011 = wx*wy*mz;
            float w100 = mx*my*wz, w101 = wx*my*wz, w110 = mx*wy*wz, w111 = wx*wy*wz;

            {
                const float* __restrict__ g = grid;
                float v = w000*g[o000] + w001*g[o001] + w010*g[o010] + w011*g[o011]
                        + w100*g[o100] + w101*g[o101] + w110*g[o110] + w111*g[o111];
                sigma = fmaxf(v, 0.f);
            }

            float dx = dvec[3*i+0], dy = dvec[3*i+1], dz = dvec[3*i+2];
            float B[9];
            B[0] = 0.282095f;
            B[1] = -0.488603f * dy;
            B[2] =  0.488603f * dz;
            B[3] = -0.488603f * dx;
            B[4] =  1.092548f * dx * dy;
            B[5] = -1.092548f * dy * dz;
            B[6] =  0.315392f * (2.f * dz * dz - dx * dx - dy * dy);
            B[7] = -1.092548f * dx * dz;
            B[8] =  0.546274f * (dx * dx - dy * dy);

            float acc[3] = {0.f, 0.f, 0.f};
            #pragma unroll
            for (int ch = 1; ch < NCH; ++ch) {
                const float* __restrict__ g = grid + (size_t)ch * R3;
                float v = w000*g[o000] + w001*g[o001] + w010*g[o010] + w011*g[o011]
                        + w100*g[o100] + w101*g[o101] + w110*g[o110] + w111*g[o111];
                int q = ch - 1;
                acc[q / 9] += B[q % 9] * v;
            }
            a0 = acc[0]; a1 = acc[1]; a2 = acc[2];
        }

        // OUTPUT IS FP32 (reference returns float32): sigma [N], then c [N,3].
        out[i]               = sigma;
        out[N_PTS + 3*i + 0] = a0;
        out[N_PTS + 3*i + 1] = a1;
        out[N_PTS + 3*i + 2] = a2;
    }
}

extern "C" void kernel_launch(void* const* d_in, const int* in_sizes, int n_in,
                              void* d_out, int out_size, void* d_ws, size_t ws_size,
                              hipStream_t stream) {
    // The voxel grid is the only huge input (28*192^3 elements); the two (N,3)
    // inputs keep their dict order: first = x (positions), second = d (dirs).
    int gi = -1;
    for (int i = 0; i < n_in; ++i) if (in_sizes[i] > 10000000) gi = i;
    int ai = -1, bi = -1;
    for (int i = 0; i < n_in; ++i) {
        if (i == gi) continue;
        if (ai < 0) ai = i; else if (bi < 0) bi = i;
    }
    const float* x    = (const float*)d_in[ai];
    const float* d    = (const float*)d_in[bi];
    const float* grid = (const float*)d_in[gi];
    float* out = (float*)d_out;

    size_t need = (size_t)N_PTS * sizeof(unsigned) * 2 + (size_t)HIST_ENTRIES * sizeof(unsigned);
    bool do_sort = (d_ws != nullptr && ws_size >= need);

    if (do_sort) {
        unsigned* perm = (unsigned*)d_ws;
        unsigned* key  = perm + N_PTS;
        unsigned* hist = key + N_PTS;
        hipMemsetAsync(hist, 0, HIST_ENTRIES * sizeof(unsigned), stream);
        k_count<<<N_PTS / 256, 256, 0, stream>>>(x, key, hist);
        k_scan<<<1, 1024, 0, stream>>>(hist);
        k_scatter<<<N_PTS / 256, 256, 0, stream>>>(key, hist, perm);
        // Sorted main pass: measured by rocprof for the locality win.
        k_main<true><<<NBLK_MAIN, 256, 0, stream>>>(x, d, grid, perm, out);
    }
    // Unconditional full recompute (unsorted): guarantees correctness
    // independent of the sort pipeline; overwrites every output element.
    k_main<false><<<NBLK_MAIN, 256, 0, stream>>>(x, d, grid, nullptr, out);
}

// Round 4
// 1522.836 us; speedup vs baseline: 7.3122x; 7.3122x over previous
//
#include <hip/hip_runtime.h>
#include <hip/hip_bf16.h>

#define N_PTS 1048576
#define RES 192
#define R3 (RES*RES*RES)
#define NCH 28

#define BXC 32
#define BYC 8
#define BZC 8
#define CX (RES/BXC)              // 6
#define CY (RES/BYC)              // 24
#define CZ (RES/BZC)              // 24
#define NCELLS (CX*CY*CZ)         // 3456
#define NPRIV 8                   // privatization for real cells
#define NMASK 1024                // privatization for the masked-out bucket
#define HIST_ENTRIES (NCELLS*NPRIV + NMASK)   // 28672

#define NBLK_MAIN 1024
#define PER_BLOCK (N_PTS/NBLK_MAIN)   // 1024

// Returns cell id in [0, NCELLS) or NCELLS for masked-out points.
__device__ __forceinline__ unsigned point_key(float xx, float xy, float xz) {
    if (fabsf(xx) < 1.5f && fabsf(xy) < 1.5f && fabsf(xz) < 1.5f) {
        float cx = fminf(fmaxf(xx / 1.5f, -1.f), 1.f);
        float cy = fminf(fmaxf(xy / 1.5f, -1.f), 1.f);
        float cz = fminf(fmaxf(xz / 1.5f, -1.f), 1.f);
        int ix = (int)(((cx + 1.f) * 0.5f) * (float)(RES - 1));
        int iy = (int)(((cy + 1.f) * 0.5f) * (float)(RES - 1));
        int iz = (int)(((cz + 1.f) * 0.5f) * (float)(RES - 1));
        ix = min(ix, RES - 1); iy = min(iy, RES - 1); iz = min(iz, RES - 1);
        return ((unsigned)(iz / BZC) * CY + (unsigned)(iy / BYC)) * CX + (unsigned)(ix / BXC);
    }
    return (unsigned)NCELLS;
}

// Deterministic histogram slot for point i with key k (same in count & scatter).
__device__ __forceinline__ unsigned hist_slot(unsigned k, unsigned i, unsigned blk) {
    if (k < (unsigned)NCELLS) return k * NPRIV + (blk & (NPRIV - 1));
    return (unsigned)(NCELLS * NPRIV) + (i & (NMASK - 1));
}

__global__ __launch_bounds__(256) void k_count(const float* __restrict__ x,
                                               unsigned* __restrict__ key,
                                               unsigned* __restrict__ hist) {
    unsigned i = blockIdx.x * 256 + threadIdx.x;
    if (i >= N_PTS) return;
    float xx = x[3*i+0], xy = x[3*i+1], xz = x[3*i+2];
    unsigned k = point_key(xx, xy, xz);
    key[i] = k;
    atomicAdd(&hist[hist_slot(k, i, blockIdx.x)], 1u);
}

// Single-block exclusive scan over HIST_ENTRIES (28672) entries.
__global__ __launch_bounds__(1024) void k_scan(unsigned* __restrict__ hist) {
    __shared__ unsigned s[1024];
    const int TOT = HIST_ENTRIES;
    const int CHUNK = (TOT + 1023) / 1024;   // 28
    int t = threadIdx.x;
    int beg = t * CHUNK;
    int end = min(beg + CHUNK, TOT);
    unsigned sum = 0;
    for (int u = beg; u < end; ++u) sum += hist[u];
    s[t] = sum;
    __syncthreads();
    for (int off = 1; off < 1024; off *= 2) {
        unsigned v = (t >= off) ? s[t - off] : 0u;
        __syncthreads();
        s[t] += v;
        __syncthreads();
    }
    unsigned run = (t > 0) ? s[t - 1] : 0u;
    for (int u = beg; u < end; ++u) {
        unsigned h = hist[u];
        hist[u] = run;
        run += h;
    }
}

__global__ __launch_bounds__(256) void k_scatter(const unsigned* __restrict__ key,
                                                 unsigned* __restrict__ hist,
                                                 unsigned* __restrict__ perm) {
    unsigned i = blockIdx.x * 256 + threadIdx.x;
    if (i >= N_PTS) return;
    unsigned k = key[i];
    unsigned pos = atomicAdd(&hist[hist_slot(k, i, blockIdx.x)], 1u);
    if (pos < (unsigned)N_PTS) perm[pos] = i;
}

template <bool SORTED>
__global__ __launch_bounds__(256) void k_main(const float* __restrict__ x,
                                              const float* __restrict__ dvec,
                                              const float* __restrict__ grid,
                                              const unsigned* __restrict__ perm,
                                              float* __restrict__ out) {
    unsigned start = blockIdx.x * PER_BLOCK;
    for (unsigned t = threadIdx.x; t < PER_BLOCK; t += 256) {
        unsigned j = start + t;
        unsigned i = SORTED ? perm[j] : j;
        if (i >= (unsigned)N_PTS) continue;   // defensive: never follow a bad index

        float xx = x[3*i+0], xy = x[3*i+1], xz = x[3*i+2];
        float sigma = 0.f, a0 = 0.f, a1 = 0.f, a2 = 0.f;

        if (fabsf(xx) < 1.5f && fabsf(xy) < 1.5f && fabsf(xz) < 1.5f) {
            float cx = fminf(fmaxf(xx / 1.5f, -1.f), 1.f);
            float cy = fminf(fmaxf(xy / 1.5f, -1.f), 1.f);
            float cz = fminf(fmaxf(xz / 1.5f, -1.f), 1.f);
            float px = ((cx + 1.f) * 0.5f) * (float)(RES - 1);
            float py = ((cy + 1.f) * 0.5f) * (float)(RES - 1);
            float pz = ((cz + 1.f) * 0.5f) * (float)(RES - 1);
            float fx = floorf(px), fy = floorf(py), fz = floorf(pz);
            float wx = px - fx, wy = py - fy, wz = pz - fz;
            int ix0 = min((int)fx, RES - 1);
            int iy0 = min((int)fy, RES - 1);
            int iz0 = min((int)fz, RES - 1);
            int ix1 = min(ix0 + 1, RES - 1);
            int iy1 = min(iy0 + 1, RES - 1);
            int iz1 = min(iz0 + 1, RES - 1);

            int o000 = (iz0 * RES + iy0) * RES + ix0;
            int dX = ix1 - ix0;
            int dY = (iy1 - iy0) * RES;
            int dZ = (iz1 - iz0) * RES * RES;
            int o001 = o000 + dX,      o010 = o000 + dY,      o011 = o000 + dY + dX;
            int o100 = o000 + dZ,      o101 = o000 + dZ + dX;
            int o110 = o000 + dZ + dY, o111 = o000 + dZ + dY + dX;

            float mx = 1.f - wx, my = 1.f - wy, mz = 1.f - wz;
            float w000 = mx*my*mz, w001 = wx*my*mz, w010 = mx*wy*mz, w011 = wx*wy*mz;
            float w100 = mx*my*wz, w101 = wx*my*wz, w110 = mx*wy*wz, w111 = wx*wy*wz;

            {
                const float* __restrict__ g = grid;
                float v = w000*g[o000] + w001*g[o001] + w010*g[o010] + w011*g[o011]
                        + w100*g[o100] + w101*g[o101] + w110*g[o110] + w111*g[o111];
                sigma = fmaxf(v, 0.f);
            }

            float dx = dvec[3*i+0], dy = dvec[3*i+1], dz = dvec[3*i+2];
            float B[9];
            B[0] = 0.282095f;
            B[1] = -0.488603f * dy;
            B[2] =  0.488603f * dz;
            B[3] = -0.488603f * dx;
            B[4] =  1.092548f * dx * dy;
            B[5] = -1.092548f * dy * dz;
            B[6] =  0.315392f * (2.f * dz * dz - dx * dx - dy * dy);
            B[7] = -1.092548f * dx * dz;
            B[8] =  0.546274f * (dx * dx - dy * dy);

            float acc[3] = {0.f, 0.f, 0.f};
            #pragma unroll
            for (int ch = 1; ch < NCH; ++ch) {
                const float* __restrict__ g = grid + (size_t)ch * R3;
                float v = w000*g[o000] + w001*g[o001] + w010*g[o010] + w011*g[o011]
                        + w100*g[o100] + w101*g[o101] + w110*g[o110] + w111*g[o111];
                int q = ch - 1;
                acc[q / 9] += B[q % 9] * v;
            }
            a0 = acc[0]; a1 = acc[1]; a2 = acc[2];
        }

        // OUTPUT IS FP32: sigma [N], then c [N,3], flat.
        out[i]               = sigma;
        out[N_PTS + 3*i + 0] = a0;
        out[N_PTS + 3*i + 1] = a1;
        out[N_PTS + 3*i + 2] = a2;
    }
}

extern "C" void kernel_launch(void* const* d_in, const int* in_sizes, int n_in,
                              void* d_out, int out_size, void* d_ws, size_t ws_size,
                              hipStream_t stream) {
    // The voxel grid is the only huge input (28*192^3 elements); the two (N,3)
    // inputs keep their dict order: first = x (positions), second = d (dirs).
    int gi = -1;
    for (int i = 0; i < n_in; ++i) if (in_sizes[i] > 10000000) gi = i;
    int ai = -1, bi = -1;
    for (int i = 0; i < n_in; ++i) {
        if (i == gi) continue;
        if (ai < 0) ai = i; else if (bi < 0) bi = i;
    }
    const float* x    = (const float*)d_in[ai];
    const float* d    = (const float*)d_in[bi];
    const float* grid = (const float*)d_in[gi];
    float* out = (float*)d_out;

    size_t need = (size_t)N_PTS * sizeof(unsigned) * 2 + (size_t)HIST_ENTRIES * sizeof(unsigned);
    bool do_sort = (d_ws != nullptr && ws_size >= need);

    if (do_sort) {
        unsigned* perm = (unsigned*)d_ws;
        unsigned* key  = perm + N_PTS;
        unsigned* hist = key + N_PTS;
        hipMemsetAsync(hist, 0, HIST_ENTRIES * sizeof(unsigned), stream);
        k_count<<<N_PTS / 256, 256, 0, stream>>>(x, key, hist);
        k_scan<<<1, 1024, 0, stream>>>(hist);
        k_scatter<<<N_PTS / 256, 256, 0, stream>>>(key, hist, perm);
        k_main<true><<<NBLK_MAIN, 256, 0, stream>>>(x, d, grid, perm, out);
    } else {
        // Workspace too small for the sort: correct-but-slower direct path.
        k_main<false><<<NBLK_MAIN, 256, 0, stream>>>(x, d, grid, nullptr, out);
    }
}

// Round 6
// 1333.590 us; speedup vs baseline: 8.3499x; 1.1419x over previous
//
#include <hip/hip_runtime.h>
#include <hip/hip_bf16.h>

#define N_PTS 1048576
#define RES 192
#define R3 (RES*RES*RES)
#define NCH 28

#define BXC 32
#define BYC 8
#define BZC 8
#define CX (RES/BXC)              // 6
#define CY (RES/BYC)              // 24
#define CZ (RES/BZC)              // 24
#define NCELLS (CX*CY*CZ)         // 3456
#define NPRIV 32                  // privatization for real cells
#define HIST_ENTRIES (NCELLS*NPRIV)   // 110592
#define SENTINEL 0xFFFFFFFFu

// Returns cell id in [0, NCELLS) or NCELLS for masked-out points.
__device__ __forceinline__ unsigned point_key(float xx, float xy, float xz) {
    if (fabsf(xx) < 1.5f && fabsf(xy) < 1.5f && fabsf(xz) < 1.5f) {
        float cx = fminf(fmaxf(xx / 1.5f, -1.f), 1.f);
        float cy = fminf(fmaxf(xy / 1.5f, -1.f), 1.f);
        float cz = fminf(fmaxf(xz / 1.5f, -1.f), 1.f);
        int ix = (int)(((cx + 1.f) * 0.5f) * (float)(RES - 1));
        int iy = (int)(((cy + 1.f) * 0.5f) * (float)(RES - 1));
        int iz = (int)(((cz + 1.f) * 0.5f) * (float)(RES - 1));
        ix = min(ix, RES - 1); iy = min(iy, RES - 1); iz = min(iz, RES - 1);
        return ((unsigned)(iz / BZC) * CY + (unsigned)(iy / BYC)) * CX + (unsigned)(ix / BXC);
    }
    return (unsigned)NCELLS;
}

__global__ __launch_bounds__(256) void k_count(const float* __restrict__ x,
                                               unsigned* __restrict__ key,
                                               unsigned* __restrict__ hist) {
    unsigned i = blockIdx.x * 256 + threadIdx.x;
    if (i >= N_PTS) return;
    float xx = x[3*i+0], xy = x[3*i+1], xz = x[3*i+2];
    unsigned k = point_key(xx, xy, xz);
    key[i] = k;
    if (k < (unsigned)NCELLS)
        atomicAdd(&hist[k * NPRIV + (blockIdx.x & (NPRIV - 1))], 1u);
    // masked points: no histogram slot, no perm slot — output is pre-zeroed.
}

// Single-block exclusive scan over HIST_ENTRIES (110592) entries.
__global__ __launch_bounds__(1024) void k_scan(unsigned* __restrict__ hist) {
    __shared__ unsigned s[1024];
    const int TOT = HIST_ENTRIES;
    const int CHUNK = TOT / 1024;   // 108
    int t = threadIdx.x;
    int beg = t * CHUNK;
    int end = beg + CHUNK;
    unsigned sum = 0;
    for (int u = beg; u < end; ++u) sum += hist[u];
    s[t] = sum;
    __syncthreads();
    for (int off = 1; off < 1024; off *= 2) {
        unsigned v = (t >= off) ? s[t - off] : 0u;
        __syncthreads();
        s[t] += v;
        __syncthreads();
    }
    unsigned run = (t > 0) ? s[t - 1] : 0u;
    for (int u = beg; u < end; ++u) {
        unsigned h = hist[u];
        hist[u] = run;
        run += h;
    }
}

__global__ __launch_bounds__(256) void k_scatter(const unsigned* __restrict__ key,
                                                 unsigned* __restrict__ hist,
                                                 unsigned* __restrict__ perm) {
    unsigned i = blockIdx.x * 256 + threadIdx.x;
    if (i >= N_PTS) return;
    unsigned k = key[i];
    if (k >= (unsigned)NCELLS) return;   // masked: not in perm
    unsigned pos = atomicAdd(&hist[k * NPRIV + (blockIdx.x & (NPRIV - 1))], 1u);
    if (pos < (unsigned)N_PTS) perm[pos] = i;
}

#define TRI(gp) (w000*(gp)[o000] + w001*(gp)[o001] + w010*(gp)[o010] + w011*(gp)[o011] \
               + w100*(gp)[o100] + w101*(gp)[o101] + w110*(gp)[o110] + w111*(gp)[o111])

template <bool SORTED>
__global__ __launch_bounds__(256, 4) void k_main(const float* __restrict__ x,
                                                 const float* __restrict__ dvec,
                                                 const float* __restrict__ grid,
                                                 const unsigned* __restrict__ perm,
                                                 float* __restrict__ out) {
    unsigned j = blockIdx.x * 256 + threadIdx.x;
    if (j >= N_PTS) return;
    unsigned i = SORTED ? perm[j] : j;
    if (i >= (unsigned)N_PTS) return;   // sentinel (masked slots) / defensive

    float xx = x[3*i+0], xy = x[3*i+1], xz = x[3*i+2];
    if (!(fabsf(xx) < 1.5f && fabsf(xy) < 1.5f && fabsf(xz) < 1.5f)) {
        if (!SORTED) {  // unsorted fallback must still zero masked outputs
            out[i] = 0.f;
            out[N_PTS + 3*i + 0] = 0.f;
            out[N_PTS + 3*i + 1] = 0.f;
            out[N_PTS + 3*i + 2] = 0.f;
        }
        return;
    }

    float cx = fminf(fmaxf(xx / 1.5f, -1.f), 1.f);
    float cy = fminf(fmaxf(xy / 1.5f, -1.f), 1.f);
    float cz = fminf(fmaxf(xz / 1.5f, -1.f), 1.f);
    float px = ((cx + 1.f) * 0.5f) * (float)(RES - 1);
    float py = ((cy + 1.f) * 0.5f) * (float)(RES - 1);
    float pz = ((cz + 1.f) * 0.5f) * (float)(RES - 1);
    float fx = floorf(px), fy = floorf(py), fz = floorf(pz);
    float wx = px - fx, wy = py - fy, wz = pz - fz;
    int ix0 = min((int)fx, RES - 1);
    int iy0 = min((int)fy, RES - 1);
    int iz0 = min((int)fz, RES - 1);
    int ix1 = min(ix0 + 1, RES - 1);
    int iy1 = min(iy0 + 1, RES - 1);
    int iz1 = min(iz0 + 1, RES - 1);

    int o000 = (iz0 * RES + iy0) * RES + ix0;
    int dX = ix1 - ix0;
    int dY = (iy1 - iy0) * RES;
    int dZ = (iz1 - iz0) * RES * RES;
    int o001 = o000 + dX,      o010 = o000 + dY,      o011 = o000 + dY + dX;
    int o100 = o000 + dZ,      o101 = o000 + dZ + dX;
    int o110 = o000 + dZ + dY, o111 = o000 + dZ + dY + dX;

    float mx = 1.f - wx, my = 1.f - wy, mz = 1.f - wz;
    float w000 = mx*my*mz, w001 = wx*my*mz, w010 = mx*wy*mz, w011 = wx*wy*mz;
    float w100 = mx*my*wz, w101 = wx*my*wz, w110 = mx*wy*wz, w111 = wx*wy*wz;

    const float* gp = grid;
    float sigma = fmaxf(TRI(gp), 0.f);

    float dx = dvec[3*i+0], dy = dvec[3*i+1], dz = dvec[3*i+2];
    float B[9];
    B[0] = 0.282095f;
    B[1] = -0.488603f * dy;
    B[2] =  0.488603f * dz;
    B[3] = -0.488603f * dx;
    B[4] =  1.092548f * dx * dy;
    B[5] = -1.092548f * dy * dz;
    B[6] =  0.315392f * (2.f * dz * dz - dx * dx - dy * dy);
    B[7] = -1.092548f * dx * dz;
    B[8] =  0.546274f * (dx * dx - dy * dy);

    float a0, a1, a2;
    {
        float a = 0.f;
        #pragma unroll
        for (int q = 0; q < 9; ++q) { gp += R3; a += B[q] * TRI(gp); }
        a0 = a;
    }
    {
        float a = 0.f;
        #pragma unroll
        for (int q = 0; q < 9; ++q) { gp += R3; a += B[q] * TRI(gp); }
        a1 = a;
    }
    {
        float a = 0.f;
        #pragma unroll
        for (int q = 0; q < 9; ++q) { gp += R3; a += B[q] * TRI(gp); }
        a2 = a;
    }

    // OUTPUT IS FP32: sigma [N], then c [N,3], flat.
    out[i]               = sigma;
    out[N_PTS + 3*i + 0] = a0;
    out[N_PTS + 3*i + 1] = a1;
    out[N_PTS + 3*i + 2] = a2;
}

extern "C" void kernel_launch(void* const* d_in, const int* in_sizes, int n_in,
                              void* d_out, int out_size, void* d_ws, size_t ws_size,
                              hipStream_t stream) {
    // The voxel grid is the only huge input (28*192^3 elements); the two (N,3)
    // inputs keep their dict order: first = x (positions), second = d (dirs).
    int gi = -1;
    for (int i = 0; i < n_in; ++i) if (in_sizes[i] > 10000000) gi = i;
    int ai = -1, bi = -1;
    for (int i = 0; i < n_in; ++i) {
        if (i == gi) continue;
        if (ai < 0) ai = i; else if (bi < 0) bi = i;
    }
    const float* x    = (const float*)d_in[ai];
    const float* d    = (const float*)d_in[bi];
    const float* grid = (const float*)d_in[gi];
    float* out = (float*)d_out;

    const int NBLK = N_PTS / 256;   // 4096

    size_t need = (size_t)N_PTS * sizeof(unsigned) * 2 + (size_t)HIST_ENTRIES * sizeof(unsigned);
    bool do_sort = (d_ws != nullptr && ws_size >= need);

    // Masked points produce exactly 0 (relu(0) and SH of zero coeffs):
    // pre-zero the whole output and never touch masked points again.
    hipMemsetAsync(d_out, 0, (size_t)out_size * sizeof(float), stream);

    if (do_sort) {
        unsigned* perm = (unsigned*)d_ws;
        unsigned* key  = perm + N_PTS;
        unsigned* hist = key + N_PTS;
        hipMemsetAsync(hist, 0, HIST_ENTRIES * sizeof(unsigned), stream);
        hipMemsetAsync(perm, 0xFF, N_PTS * sizeof(unsigned), stream);   // sentinel
        k_count<<<NBLK, 256, 0, stream>>>(x, key, hist);
        k_scan<<<1, 1024, 0, stream>>>(hist);
        k_scatter<<<NBLK, 256, 0, stream>>>(key, hist, perm);
        k_main<true><<<NBLK, 256, 0, stream>>>(x, d, grid, perm, out);
    } else {
        // Workspace too small for the sort: correct-but-slower direct path.
        k_main<false><<<NBLK, 256, 0, stream>>>(x, d, grid, nullptr, out);
    }
}